// Round 18
// baseline (145.306 us; speedup 1.0000x reference)
//
#include <hip/hip_runtime.h>
#include <stdint.h>
#include <math.h>

#define NB 4
#define NN 4096
#define NF 256
#define ND 128
#define KVB 64           // kv rows per tile (r18: 32->64, amortize per-tile costs)
#define NR (NB * NN)
#define QKVE ((size_t)NR * ND)      // 2,097,152 elements

typedef __bf16 bf16x8 __attribute__((ext_vector_type(8)));
typedef __bf16 bf16x4v __attribute__((ext_vector_type(4)));
typedef float f32x4 __attribute__((ext_vector_type(4)));
typedef int i32x4 __attribute__((ext_vector_type(4)));
typedef unsigned short u16x4 __attribute__((ext_vector_type(4)));

__device__ __forceinline__ unsigned short f2bf(float f) {
    union { float f; uint32_t u; } v; v.f = f;
    uint32_t r = (v.u + 0x7FFFu + ((v.u >> 16) & 1u)) >> 16;
    return (unsigned short)r;
}
__device__ __forceinline__ bf16x8 lds_read16(const unsigned short* base, int byte_off) {
    return *reinterpret_cast<const bf16x8*>(reinterpret_cast<const char*>(base) + byte_off);
}
__device__ __forceinline__ void gld_lds16(const void* g, void* l) {
    __builtin_amdgcn_global_load_lds(
        (const __attribute__((address_space(1))) void*)g,
        (__attribute__((address_space(3))) void*)l, 16, 0, 0);
}
__device__ __forceinline__ i32x4 nt_load4(const int* p) {
    return __builtin_nontemporal_load(reinterpret_cast<const i32x4*>(p));
}

// ---------------- Kernel 1: QKV projection (r17, proven) ----------------------
// V written in B-frag tile order: VS[b][tile32(128)][chunk(4)][d(128)][m8]
__global__ __launch_bounds__(256) void qkv_proj(
    const float* __restrict__ h,
    const float* __restrict__ Wq, const float* __restrict__ bq,
    const float* __restrict__ Wk, const float* __restrict__ bk,
    const float* __restrict__ Wv, const float* __restrict__ bv,
    unsigned short* __restrict__ qo, unsigned short* __restrict__ ko,
    unsigned short* __restrict__ vs, float qscale)
{
    __shared__ unsigned short h_lds[64 * 128];
    __shared__ unsigned short w_lds[128 * 128];

    const int tid = threadIdx.x;
    const int lane = tid & 63;
    const int proj = blockIdx.x >> 8;          // 0=Q,1=K,2=V
    const int R0 = (blockIdx.x & 255) * 64;
    const int wv = tid >> 6;
    const int l15 = lane & 15;
    const int lhi = lane >> 4;

    const float* W    = proj == 0 ? Wq : (proj == 1 ? Wk : Wv);
    const float* bias = proj == 0 ? bq : (proj == 1 ? bk : bv);
    const float scale = proj == 0 ? qscale : 1.0f;

    f32x4 acc[8];
#pragma unroll
    for (int i = 0; i < 8; ++i) acc[i] = f32x4{0.f, 0.f, 0.f, 0.f};

    for (int kc = 0; kc < 2; ++kc) {
        const int c0 = kc * 128;
        __syncthreads();
#pragma unroll
        for (int p = 0; p < 8; ++p) {
            int i2 = p * 256 + tid;
            int row = i2 >> 5;
            int seg = i2 & 31;
            f32x4 hv = *reinterpret_cast<const f32x4*>(h + (size_t)(R0 + row) * NF + c0 + seg * 4);
            u16x4 hb;
            hb[0] = f2bf(hv[0]); hb[1] = f2bf(hv[1]); hb[2] = f2bf(hv[2]); hb[3] = f2bf(hv[3]);
            int byte = (row * 256 + seg * 8) ^ ((row & 7) << 4);
            *reinterpret_cast<u16x4*>(reinterpret_cast<char*>(h_lds) + byte) = hb;
        }
#pragma unroll
        for (int p = 0; p < 16; ++p) {
            int i2 = p * 256 + tid;
            int row = i2 >> 5;
            int seg = i2 & 31;
            f32x4 wv4 = *reinterpret_cast<const f32x4*>(W + (size_t)row * NF + c0 + seg * 4);
            u16x4 wb;
            wb[0] = f2bf(wv4[0]); wb[1] = f2bf(wv4[1]); wb[2] = f2bf(wv4[2]); wb[3] = f2bf(wv4[3]);
            int byte = (row * 256 + seg * 8) ^ ((row & 7) << 4);
            *reinterpret_cast<u16x4*>(reinterpret_cast<char*>(w_lds) + byte) = wb;
        }
        __syncthreads();
        const int arow = 16 * wv + l15;
#pragma unroll
        for (int ks = 0; ks < 4; ++ks) {
            int k = ks * 32 + 8 * lhi;
            bf16x8 a = lds_read16(h_lds, (arow * 256 + k * 2) ^ ((arow & 7) << 4));
#pragma unroll
            for (int cs = 0; cs < 8; ++cs) {
                int d = 16 * cs + l15;
                bf16x8 b = lds_read16(w_lds, (d * 256 + k * 2) ^ ((d & 7) << 4));
                acc[cs] = __builtin_amdgcn_mfma_f32_16x16x32_bf16(a, b, acc[cs], 0, 0, 0);
            }
        }
    }
    if (proj < 2) {
        unsigned short* out = proj == 0 ? qo : ko;
#pragma unroll
        for (int cs = 0; cs < 8; ++cs) {
            int d = 16 * cs + l15;
            float bb = bias[d];
#pragma unroll
            for (int j = 0; j < 4; ++j) {
                int row = R0 + 16 * wv + 4 * lhi + j;
                out[(size_t)row * ND + d] = f2bf((acc[cs][j] + bb) * scale);
            }
        }
    } else {
        const int bb_ = R0 >> 12;
        const int nb_ = (R0 & (NN - 1)) + 16 * wv + 4 * lhi;
        const int pt = nb_ >> 5;
        const int ch = (nb_ >> 3) & 3;
        const int mm0 = nb_ & 7;
#pragma unroll
        for (int cs = 0; cs < 8; ++cs) {
            int d = 16 * cs + l15;
            float bb = bias[d];
            u16x4 o;
#pragma unroll
            for (int j = 0; j < 4; ++j) o[j] = f2bf(acc[cs][j] + bb);
            size_t oidx = ((size_t)(bb_ * 128 + pt)) * 4096 + ch * 1024 + d * 8 + mm0;
            *reinterpret_cast<u16x4*>(vs + oidx) = o;
        }
    }
}

// -------- Kernel 2: LDS-staged flash attention, KVB=64, direct-nt adj ---------
// r18 vs r17: 64 kv rows per tile -> one barrier / vote / m-l update /
// P-roundtrip per 2x work (per-tile fixed costs halve). adj read nontemporal
// (single-use 268MB stream must not evict the block's K/V L2 set). Mask uses
// ONE raw reg buffer + packed bits: pack at compute start (loads landed a full
// phase ago), then reuse the raw regs for the next tile's loads.
__global__ __launch_bounds__(256, 2) void attn(
    const unsigned short* __restrict__ Q,   // [B*N,128] bf16, scaled 1/(sqrt(128)*ln2)
    const unsigned short* __restrict__ K,   // [B*N,128] bf16 row-major
    const unsigned short* __restrict__ VS,  // tiled V (see proj)
    const int* __restrict__ adj,            // [B,N,N] i32
    float* __restrict__ out,                // split-0 partial O (and final out)
    float* __restrict__ opart1,             // splits 1.. partial O (f32)
    float* __restrict__ ml,                 // [nsplit][NR][2] (m, l) log2-domain
    int ntl)                                // 64-row tiles per split (16 or 32)
{
    __shared__ unsigned short stA[16384];  // [0..8191]=K frags, [8192..16383]=V frags
    __shared__ unsigned short stB[16384];
    __shared__ unsigned short p_lds[8192]; // 4 waves x 2 groups x 2KB P^T tiles

    const int tid = threadIdx.x;
    const int lane = tid & 63;
    const int w = tid >> 6;
    const int l15 = lane & 15;
    const int lhi = lane >> 4;

    const int flat = blockIdx.x;
    const int x = flat & 7;
    const int rest = flat >> 3;
    const int qt = rest & 31;
    const int s2 = rest >> 5;
    const int combo = x + 8 * s2;
    const int b = combo & 3;
    const int sp = combo >> 2;
    const int q0w = qt * 128 + w * 32;
    const size_t bN = (size_t)b * NN;
    const int ptbase = sp * ntl;

    const unsigned short* Kb = K + bN * ND;
    const unsigned short* Vbase = VS + (size_t)b * 128 * 4096;
    const int* adjb = adj + (size_t)b * NN * NN + (size_t)(q0w + l15) * NN + 4 * lhi;

    bf16x8 qf[2][4];
#pragma unroll
    for (int g = 0; g < 2; ++g)
#pragma unroll
        for (int ks = 0; ks < 4; ++ks)
            qf[g][ks] = *reinterpret_cast<const bf16x8*>(
                Q + (bN + q0w + g * 16 + l15) * ND + ks * 32 + 8 * lhi);

    f32x4 acc[2][8];
#pragma unroll
    for (int g = 0; g < 2; ++g)
#pragma unroll
        for (int i = 0; i < 8; ++i) acc[g][i] = f32x4{0.f, 0.f, 0.f, 0.f};
    float m_run[2] = {-INFINITY, -INFINITY};
    float l_part[2] = {0.f, 0.f};

    // stage one 64-row KV tile: 32 x 1KB chunks (8 per wave).
    auto stage = [&](unsigned short* st, int pt) {
        const int m0 = pt * KVB;
#pragma unroll
        for (int i = 0; i < 8; ++i) {
            int c = w * 8 + i;                  // 0..31, wave-uniform
            if (c < 16) {                       // K frag block c = ms*4+ks
                int ms = c >> 2, ks = c & 3;
                const unsigned short* src = Kb
                    + (size_t)(m0 + ms * 16 + l15) * ND + ks * 32 + lhi * 8;
                gld_lds16(src, st + c * 512);
            } else {                            // V chunk (2 consecutive VS tile images)
                int vi = c - 16;
                const unsigned short* src = Vbase + (size_t)pt * 8192 + vi * 512 + lane * 8;
                gld_lds16(src, st + 8192 + vi * 512);
            }
        }
    };
    // issue nt adj loads for tile pt into the (reused) raw buffer
    auto adjld = [&](i32x4 (&raw)[2][4], int pt) {
        const int m0 = pt * KVB;
#pragma unroll
        for (int g = 0; g < 2; ++g)
#pragma unroll
            for (int ms = 0; ms < 4; ++ms)
                raw[g][ms] = nt_load4(adjb + (size_t)(g * 16) * NN + m0 + 16 * ms);
    };

    i32x4 rawm[2][4];

    auto compute = [&](const unsigned short* st, int ptn) {
        // ---- pack last-phase's adj loads (landed long ago), then reuse regs
        unsigned int mk[2];
#pragma unroll
        for (int g = 0; g < 2; ++g) {
            unsigned int bits = 0;
#pragma unroll
            for (int ms = 0; ms < 4; ++ms)
#pragma unroll
                for (int r = 0; r < 4; ++r)
                    bits |= (rawm[g][ms][r] != 0 ? 1u : 0u) << (4 * ms + r);
            mk[g] = bits;
        }
        adjld(rawm, ptn);   // issue next tile's adj loads (land during this phase)

        // ---- S^T = mfma(K, Q): 4 m-subtiles x 4 k-slices per g
        f32x4 s[2][4];
#pragma unroll
        for (int g = 0; g < 2; ++g)
#pragma unroll
            for (int ms = 0; ms < 4; ++ms) s[g][ms] = f32x4{0.f, 0.f, 0.f, 0.f};
        __builtin_amdgcn_s_setprio(1);
#pragma unroll
        for (int ms = 0; ms < 4; ++ms) {
            bf16x8 kf[4];
#pragma unroll
            for (int ks = 0; ks < 4; ++ks)
                kf[ks] = lds_read16(st, (ms * 4 + ks) * 1024 + lane * 16);
#pragma unroll
            for (int g = 0; g < 2; ++g)
#pragma unroll
                for (int ks = 0; ks < 4; ++ks)
                    s[g][ms] = __builtin_amdgcn_mfma_f32_16x16x32_bf16(
                        kf[ks], qf[g][ks], s[g][ms], 0, 0, 0);
        }
        __builtin_amdgcn_s_setprio(0);

        // ---- mask + local max + defer-max vote
        float smaxl[2];
        float dmax = -INFINITY;
#pragma unroll
        for (int g = 0; g < 2; ++g) {
            float mx = -INFINITY;
#pragma unroll
            for (int ms = 0; ms < 4; ++ms)
#pragma unroll
                for (int r = 0; r < 4; ++r) {
                    if (!((mk[g] >> (4 * ms + r)) & 1u)) s[g][ms][r] = -1.0e30f;
                    mx = fmaxf(mx, s[g][ms][r]);
                }
            smaxl[g] = mx;
            dmax = fmaxf(dmax, mx - m_run[g]);
        }
        if (!__all(dmax <= 8.0f)) {        // rare after warm-up
#pragma unroll
            for (int g = 0; g < 2; ++g) {
                float mx = smaxl[g];
                mx = fmaxf(mx, __shfl_xor(mx, 16, 64));
                mx = fmaxf(mx, __shfl_xor(mx, 32, 64));
                float mnew = fmaxf(m_run[g], mx);
                float c = exp2f(m_run[g] - mnew);
                m_run[g] = mnew;
                l_part[g] *= c;
#pragma unroll
                for (int ds = 0; ds < 8; ++ds) acc[g][ds] *= c;
            }
        }

        // ---- p (bf16-rounded; l matches PV weights), P roundtrip
        bf16x8 pa[2][2];
#pragma unroll
        for (int g = 0; g < 2; ++g) {
            bf16x4v pbv[4];
#pragma unroll
            for (int ms = 0; ms < 4; ++ms)
#pragma unroll
                for (int r = 0; r < 4; ++r) {
                    float p = exp2f(s[g][ms][r] - m_run[g]);   // p <= 2^8
                    __bf16 pb = (__bf16)p;
                    l_part[g] += (float)pb;
                    pbv[ms][r] = pb;
                }
            const int base = (w * 2 + g) * 2048 + l15 * 128;   // 16q x 64m tile
#pragma unroll
            for (int ms = 0; ms < 4; ++ms)
                *reinterpret_cast<bf16x4v*>(reinterpret_cast<char*>(p_lds)
                    + base + ms * 32 + lhi * 8) = pbv[ms];
            pa[g][0] = lds_read16(p_lds, base + lhi * 16);
            pa[g][1] = lds_read16(p_lds, base + 64 + lhi * 16);
        }

        // ---- O^T += mfma(V, P): 2 k-windows x 8 d-subtiles, V shared across g
        __builtin_amdgcn_s_setprio(1);
#pragma unroll
        for (int kwin = 0; kwin < 2; ++kwin)
#pragma unroll
            for (int ds = 0; ds < 8; ++ds) {
                bf16x8 vf = lds_read16(st + 8192 + kwin * 4096,
                                       lhi * 2048 + ds * 256 + l15 * 16);
#pragma unroll
                for (int g = 0; g < 2; ++g)
                    acc[g][ds] = __builtin_amdgcn_mfma_f32_16x16x32_bf16(
                        vf, pa[g][kwin], acc[g][ds], 0, 0, 0);
            }
        __builtin_amdgcn_s_setprio(0);
    };

    // ---- pipeline: stage(t+1) before compute(t); one __syncthreads per tile
    stage(stA, ptbase);
    adjld(rawm, ptbase);
    __syncthreads();

    for (int t = 0; t < ntl; t += 2) {
        stage(stB, ptbase + t + 1);
        compute(stA, ptbase + t + 1);
        __syncthreads();
        int t2 = (t + 2 < ntl) ? t + 2 : ntl - 1;
        stage(stA, ptbase + t2);
        compute(stB, ptbase + t2);
        __syncthreads();
    }

    // ---- epilogue: deferred cross-lhi l reduction (2 shfls, linear=exact)
#pragma unroll
    for (int g = 0; g < 2; ++g) {
        float rs = l_part[g];
        rs += __shfl_xor(rs, 16, 64);
        rs += __shfl_xor(rs, 32, 64);
        l_part[g] = rs;
    }

    float* op = (sp == 0) ? out : (opart1 + (size_t)(sp - 1) * NR * ND);
#pragma unroll
    for (int g = 0; g < 2; ++g) {
        const size_t rowbase = (bN + q0w + g * 16 + l15) * ND;
#pragma unroll
        for (int ds = 0; ds < 8; ++ds)
            *reinterpret_cast<f32x4*>(op + rowbase + 16 * ds + 4 * lhi) = acc[g][ds];
    }
    if (lhi == 0) {
#pragma unroll
        for (int g = 0; g < 2; ++g) {
            size_t gr = bN + q0w + g * 16 + l15;
            *reinterpret_cast<float2*>(ml + ((size_t)sp * NR + gr) * 2) =
                make_float2(m_run[g], l_part[g]);
        }
    }
}

// ---------------- Kernel 3: merge the KV-splits (m is log2-domain) -------------
__global__ __launch_bounds__(256) void merge_splits(
    float* __restrict__ out, const float* __restrict__ opart1,
    const float* __restrict__ ml, int nsplit)
{
    int idx = blockIdx.x * 256 + threadIdx.x;
    int row = idx >> 5;
    int d4 = (idx & 31) * 4;
    float mmax = ml[(size_t)row * 2];
    for (int sp = 1; sp < nsplit; ++sp)
        mmax = fmaxf(mmax, ml[((size_t)sp * NR + row) * 2]);
    f32x4 o0 = *reinterpret_cast<const f32x4*>(out + (size_t)row * ND + d4);
    float w0 = exp2f(ml[(size_t)row * 2] - mmax);
    float lsum = ml[(size_t)row * 2 + 1] * w0;
    f32x4 acc;
#pragma unroll
    for (int j = 0; j < 4; ++j) acc[j] = o0[j] * w0;
    for (int sp = 1; sp < nsplit; ++sp) {
        float m_s = ml[((size_t)sp * NR + row) * 2];
        float l_s = ml[((size_t)sp * NR + row) * 2 + 1];
        float ws_ = exp2f(m_s - mmax);
        f32x4 os = *reinterpret_cast<const f32x4*>(opart1 + ((size_t)(sp - 1) * NR + row) * ND + d4);
#pragma unroll
        for (int j = 0; j < 4; ++j) acc[j] += os[j] * ws_;
        lsum += l_s * ws_;
    }
    float inv = 1.0f / lsum;
    f32x4 r;
#pragma unroll
    for (int j = 0; j < 4; ++j) r[j] = acc[j] * inv;
    *reinterpret_cast<f32x4*>(out + (size_t)row * ND + d4) = r;
}

extern "C" void kernel_launch(void* const* d_in, const int* in_sizes, int n_in,
                              void* d_out, int out_size, void* d_ws, size_t ws_size,
                              hipStream_t stream) {
    const float* h  = (const float*)d_in[0];
    const int* adj  = (const int*)d_in[1];
    const float* Wq = (const float*)d_in[2];
    const float* bq = (const float*)d_in[3];
    const float* Wk = (const float*)d_in[4];
    const float* bk = (const float*)d_in[5];
    const float* Wv = (const float*)d_in[6];
    const float* bv = (const float*)d_in[7];
    float* out = (float*)d_out;

    unsigned short* qws  = (unsigned short*)d_ws;
    unsigned short* kws  = qws + QKVE;
    unsigned short* vsws = kws + QKVE;
    float* opart1 = (float*)(vsws + QKVE);

    const size_t need4 = 3 * QKVE * 2 + 3 * QKVE * 4 + 4 * (size_t)NR * 2 * 4;
    const int nsplit = (ws_size >= need4) ? 4 : 2;
    float* mlws = opart1 + (size_t)(nsplit - 1) * NR * ND;
    const int ntl = (NN / KVB) / nsplit;                          // 16 or 32

    // 1/(sqrt(128) * ln2): scores land in log2 units -> exp2 softmax
    const float qscale = (float)(0.08838834764831845 / 0.6931471805599453);

    qkv_proj<<<dim3(768), 256, 0, stream>>>(
        h, Wq, bq, Wk, bk, Wv, bv, qws, kws, vsws, qscale);
    attn<<<dim3(32 * 4 * nsplit), 256, 0, stream>>>(
        qws, kws, vsws, adj, out, opart1, mlws, ntl);
    merge_splits<<<dim3(NR * 32 / 256), 256, 0, stream>>>(out, opart1, mlws, nsplit);
}

// Round 19
// 124.474 us; speedup vs baseline: 1.1674x; 1.1674x over previous
//
#include <hip/hip_runtime.h>
#include <stdint.h>
#include <math.h>

#define NB 4
#define NN 4096
#define NF 256
#define ND 128
#define KVB 32
#define NR (NB * NN)
#define QKVE ((size_t)NR * ND)      // 2,097,152 elements

typedef __bf16 bf16x8 __attribute__((ext_vector_type(8)));
typedef __bf16 bf16x4v __attribute__((ext_vector_type(4)));
typedef float f32x4 __attribute__((ext_vector_type(4)));
typedef int i32x4 __attribute__((ext_vector_type(4)));
typedef unsigned short u16x4 __attribute__((ext_vector_type(4)));

__device__ __forceinline__ unsigned short f2bf(float f) {
    union { float f; uint32_t u; } v; v.f = f;
    uint32_t r = (v.u + 0x7FFFu + ((v.u >> 16) & 1u)) >> 16;
    return (unsigned short)r;
}
__device__ __forceinline__ bf16x8 lds_read16(const unsigned short* base, int byte_off) {
    return *reinterpret_cast<const bf16x8*>(reinterpret_cast<const char*>(base) + byte_off);
}
__device__ __forceinline__ void gld_lds16(const void* g, void* l) {
    __builtin_amdgcn_global_load_lds(
        (const __attribute__((address_space(1))) void*)g,
        (__attribute__((address_space(3))) void*)l, 16, 0, 0);
}

// ---------------- Kernel 1: QKV projection ------------------------------------
// V written in B-frag tile order: VS[b][tile(128)][chunk(4)][d(128)][m8]
__global__ __launch_bounds__(256) void qkv_proj(
    const float* __restrict__ h,
    const float* __restrict__ Wq, const float* __restrict__ bq,
    const float* __restrict__ Wk, const float* __restrict__ bk,
    const float* __restrict__ Wv, const float* __restrict__ bv,
    unsigned short* __restrict__ qo, unsigned short* __restrict__ ko,
    unsigned short* __restrict__ vs, float qscale)
{
    __shared__ unsigned short h_lds[64 * 128];
    __shared__ unsigned short w_lds[128 * 128];

    const int tid = threadIdx.x;
    const int lane = tid & 63;
    const int proj = blockIdx.x >> 8;          // 0=Q,1=K,2=V
    const int R0 = (blockIdx.x & 255) * 64;
    const int wv = tid >> 6;
    const int l15 = lane & 15;
    const int lhi = lane >> 4;

    const float* W    = proj == 0 ? Wq : (proj == 1 ? Wk : Wv);
    const float* bias = proj == 0 ? bq : (proj == 1 ? bk : bv);
    const float scale = proj == 0 ? qscale : 1.0f;

    f32x4 acc[8];
#pragma unroll
    for (int i = 0; i < 8; ++i) acc[i] = f32x4{0.f, 0.f, 0.f, 0.f};

    for (int kc = 0; kc < 2; ++kc) {
        const int c0 = kc * 128;
        __syncthreads();
#pragma unroll
        for (int p = 0; p < 8; ++p) {
            int i2 = p * 256 + tid;
            int row = i2 >> 5;
            int seg = i2 & 31;
            f32x4 hv = *reinterpret_cast<const f32x4*>(h + (size_t)(R0 + row) * NF + c0 + seg * 4);
            u16x4 hb;
            hb[0] = f2bf(hv[0]); hb[1] = f2bf(hv[1]); hb[2] = f2bf(hv[2]); hb[3] = f2bf(hv[3]);
            int byte = (row * 256 + seg * 8) ^ ((row & 7) << 4);
            *reinterpret_cast<u16x4*>(reinterpret_cast<char*>(h_lds) + byte) = hb;
        }
#pragma unroll
        for (int p = 0; p < 16; ++p) {
            int i2 = p * 256 + tid;
            int row = i2 >> 5;
            int seg = i2 & 31;
            f32x4 wv4 = *reinterpret_cast<const f32x4*>(W + (size_t)row * NF + c0 + seg * 4);
            u16x4 wb;
            wb[0] = f2bf(wv4[0]); wb[1] = f2bf(wv4[1]); wb[2] = f2bf(wv4[2]); wb[3] = f2bf(wv4[3]);
            int byte = (row * 256 + seg * 8) ^ ((row & 7) << 4);
            *reinterpret_cast<u16x4*>(reinterpret_cast<char*>(w_lds) + byte) = wb;
        }
        __syncthreads();
        const int arow = 16 * wv + l15;
#pragma unroll
        for (int ks = 0; ks < 4; ++ks) {
            int k = ks * 32 + 8 * lhi;
            bf16x8 a = lds_read16(h_lds, (arow * 256 + k * 2) ^ ((arow & 7) << 4));
#pragma unroll
            for (int cs = 0; cs < 8; ++cs) {
                int d = 16 * cs + l15;
                bf16x8 b = lds_read16(w_lds, (d * 256 + k * 2) ^ ((d & 7) << 4));
                acc[cs] = __builtin_amdgcn_mfma_f32_16x16x32_bf16(a, b, acc[cs], 0, 0, 0);
            }
        }
    }
    if (proj < 2) {
        unsigned short* out = proj == 0 ? qo : ko;
#pragma unroll
        for (int cs = 0; cs < 8; ++cs) {
            int d = 16 * cs + l15;
            float bb = bias[d];
#pragma unroll
            for (int j = 0; j < 4; ++j) {
                int row = R0 + 16 * wv + 4 * lhi + j;
                out[(size_t)row * ND + d] = f2bf((acc[cs][j] + bb) * scale);
            }
        }
    } else {
        const int bb_ = R0 >> 12;
        const int nb_ = (R0 & (NN - 1)) + 16 * wv + 4 * lhi;
        const int pt = nb_ >> 5;
        const int ch = (nb_ >> 3) & 3;
        const int mm0 = nb_ & 7;
#pragma unroll
        for (int cs = 0; cs < 8; ++cs) {
            int d = 16 * cs + l15;
            float bb = bias[d];
            u16x4 o;
#pragma unroll
            for (int j = 0; j < 4; ++j) o[j] = f2bf(acc[cs][j] + bb);
            size_t oidx = ((size_t)(bb_ * 128 + pt)) * 4096 + ch * 1024 + d * 8 + mm0;
            *reinterpret_cast<u16x4*>(vs + oidx) = o;
        }
    }
}

// -------- Kernel 2: LDS-staged flash attention, DIRECT adj masking -------------
// r17 configuration (verified best, 124.6us total): KVB=32, K/V staged to LDS
// once per block via global_load_lds, adj streamed directly from HBM into the
// compute phase (no pack pass), swapped-operand lane-local softmax in log2
// domain, defer-max THR=8, bf16-rounded l, KV-split 4 + merge.
__global__ __launch_bounds__(256, 2) void attn(
    const unsigned short* __restrict__ Q,   // [B*N,128] bf16, scaled 1/(sqrt(128)*ln2)
    const unsigned short* __restrict__ K,   // [B*N,128] bf16 row-major
    const unsigned short* __restrict__ VS,  // tiled V (see proj)
    const int* __restrict__ adj,            // [B,N,N] i32
    float* __restrict__ out,                // split-0 partial O (and final out)
    float* __restrict__ opart1,             // splits 1.. partial O (f32)
    float* __restrict__ ml,                 // [nsplit][NR][2] (m, l) log2-domain
    int ntl)                                // tiles per split (32 or 64)
{
    __shared__ unsigned short stA[8192];   // [0..4095]=K frags, [4096..8191]=V frags
    __shared__ unsigned short stB[8192];
    __shared__ unsigned short p_lds[4096]; // 4 waves x 2 groups x 1KB P^T tiles

    const int tid = threadIdx.x;
    const int lane = tid & 63;
    const int w = tid >> 6;
    const int l15 = lane & 15;
    const int lhi = lane >> 4;

    const int flat = blockIdx.x;
    const int x = flat & 7;
    const int rest = flat >> 3;
    const int qt = rest & 31;
    const int s2 = rest >> 5;
    const int combo = x + 8 * s2;
    const int b = combo & 3;
    const int sp = combo >> 2;
    const int q0w = qt * 128 + w * 32;
    const size_t bN = (size_t)b * NN;
    const int ptbase = sp * ntl;

    const unsigned short* Kb = K + bN * ND;
    const unsigned short* Vbase = VS + (size_t)b * 128 * 4096;
    const int* adjb = adj + (size_t)b * NN * NN + (size_t)(q0w + l15) * NN + 4 * lhi;

    bf16x8 qf[2][4];
#pragma unroll
    for (int g = 0; g < 2; ++g)
#pragma unroll
        for (int ks = 0; ks < 4; ++ks)
            qf[g][ks] = *reinterpret_cast<const bf16x8*>(
                Q + (bN + q0w + g * 16 + l15) * ND + ks * 32 + 8 * lhi);

    f32x4 acc[2][8];
#pragma unroll
    for (int g = 0; g < 2; ++g)
#pragma unroll
        for (int i = 0; i < 8; ++i) acc[g][i] = f32x4{0.f, 0.f, 0.f, 0.f};
    float m_run[2] = {-INFINITY, -INFINITY};
    float l_part[2] = {0.f, 0.f};

    auto stage = [&](unsigned short* st, int pt) {
        const int m0 = pt * KVB;
#pragma unroll
        for (int i = 0; i < 4; ++i) {
            int c = w * 4 + i;                  // 0..15, wave-uniform
            if (c < 8) {                        // K frag block c = ms*4+ks
                int ms = c >> 2, ks = c & 3;
                const unsigned short* src = Kb
                    + (size_t)(m0 + ms * 16 + l15) * ND + ks * 32 + lhi * 8;
                gld_lds16(src, st + c * 512);
            } else {                            // V chunk (VS tile is the LDS image)
                int vi = c - 8;
                const unsigned short* src = Vbase + (size_t)pt * 4096 + vi * 512 + lane * 8;
                gld_lds16(src, st + 4096 + vi * 512);
            }
        }
    };
    // direct adj mask load: this lane's 8 ints per g (rows q0w+16g+l15)
    auto adjld = [&](i32x4 (&ma)[2][2], int pt) {
        const int m0 = pt * KVB;
#pragma unroll
        for (int g = 0; g < 2; ++g)
#pragma unroll
            for (int ms = 0; ms < 2; ++ms)
                ma[g][ms] = *reinterpret_cast<const i32x4*>(
                    adjb + (size_t)(g * 16) * NN + m0 + 16 * ms);
    };

    auto compute = [&](const unsigned short* st, const i32x4 (&ma)[2][2]) {
        bf16x8 kf[2][4];
#pragma unroll
        for (int ms = 0; ms < 2; ++ms)
#pragma unroll
            for (int ks = 0; ks < 4; ++ks)
                kf[ms][ks] = lds_read16(st, (ms * 4 + ks) * 1024 + lane * 16);

        f32x4 s[2][2];
#pragma unroll
        for (int g = 0; g < 2; ++g)
#pragma unroll
            for (int ms = 0; ms < 2; ++ms) s[g][ms] = f32x4{0.f, 0.f, 0.f, 0.f};
        __builtin_amdgcn_s_setprio(1);
#pragma unroll
        for (int g = 0; g < 2; ++g)
#pragma unroll
            for (int ms = 0; ms < 2; ++ms)
#pragma unroll
                for (int ks = 0; ks < 4; ++ks)
                    s[g][ms] = __builtin_amdgcn_mfma_f32_16x16x32_bf16(
                        kf[ms][ks], qf[g][ks], s[g][ms], 0, 0, 0);
        __builtin_amdgcn_s_setprio(0);

        bf16x8 vf[8];
#pragma unroll
        for (int ds = 0; ds < 8; ++ds)
            vf[ds] = lds_read16(st + 4096, lhi * 2048 + ds * 256 + l15 * 16);

        float smaxl[2];
        float dmax = -INFINITY;
#pragma unroll
        for (int g = 0; g < 2; ++g) {
#pragma unroll
            for (int ms = 0; ms < 2; ++ms)
#pragma unroll
                for (int r = 0; r < 4; ++r)
                    if (ma[g][ms][r] == 0) s[g][ms][r] = -1.0e30f;
            float mx = fmaxf(fmaxf(fmaxf(s[g][0][0], s[g][0][1]), fmaxf(s[g][0][2], s[g][0][3])),
                             fmaxf(fmaxf(s[g][1][0], s[g][1][1]), fmaxf(s[g][1][2], s[g][1][3])));
            smaxl[g] = mx;
            dmax = fmaxf(dmax, mx - m_run[g]);
        }
        if (!__all(dmax <= 8.0f)) {        // rare after warm-up
#pragma unroll
            for (int g = 0; g < 2; ++g) {
                float mx = smaxl[g];
                mx = fmaxf(mx, __shfl_xor(mx, 16, 64));
                mx = fmaxf(mx, __shfl_xor(mx, 32, 64));
                float mnew = fmaxf(m_run[g], mx);
                float c = exp2f(m_run[g] - mnew);
                m_run[g] = mnew;
                l_part[g] *= c;
#pragma unroll
                for (int ds = 0; ds < 8; ++ds) acc[g][ds] *= c;
            }
        }

#pragma unroll
        for (int g = 0; g < 2; ++g) {
            bf16x4v pbv[2];
#pragma unroll
            for (int ms = 0; ms < 2; ++ms)
#pragma unroll
                for (int r = 0; r < 4; ++r) {
                    float p = exp2f(s[g][ms][r] - m_run[g]);   // p <= 2^8
                    __bf16 pb = (__bf16)p;
                    l_part[g] += (float)pb;    // l matches PV weights exactly
                    pbv[ms][r] = pb;
                }
            const int base = (w * 2 + g) * 1024 + l15 * 64;
#pragma unroll
            for (int ms = 0; ms < 2; ++ms)
                *reinterpret_cast<bf16x4v*>(reinterpret_cast<char*>(p_lds)
                    + base + ms * 32 + lhi * 8) = pbv[ms];
            bf16x8 pa = lds_read16(p_lds, base + lhi * 16);
            __builtin_amdgcn_s_setprio(1);
#pragma unroll
            for (int ds = 0; ds < 8; ++ds)
                acc[g][ds] = __builtin_amdgcn_mfma_f32_16x16x32_bf16(
                    vf[ds], pa, acc[g][ds], 0, 0, 0);
            __builtin_amdgcn_s_setprio(0);
        }
    };

    // ---- pipeline: stage/adj-load(t+1) issued before compute(t); sync per tile
    i32x4 maskA[2][2], maskB[2][2];
    stage(stA, ptbase);
    adjld(maskA, ptbase);
    __syncthreads();

    for (int t = 0; t < ntl; t += 2) {
        stage(stB, ptbase + t + 1);
        adjld(maskB, ptbase + t + 1);
        compute(stA, maskA);
        __syncthreads();
        int t2 = (t + 2 < ntl) ? t + 2 : ntl - 1;
        stage(stA, ptbase + t2);
        adjld(maskA, ptbase + t2);
        compute(stB, maskB);
        __syncthreads();
    }

    // ---- epilogue: deferred cross-lhi l reduction (2 shfls, linear=exact)
#pragma unroll
    for (int g = 0; g < 2; ++g) {
        float rs = l_part[g];
        rs += __shfl_xor(rs, 16, 64);
        rs += __shfl_xor(rs, 32, 64);
        l_part[g] = rs;
    }

    float* op = (sp == 0) ? out : (opart1 + (size_t)(sp - 1) * NR * ND);
#pragma unroll
    for (int g = 0; g < 2; ++g) {
        const size_t rowbase = (bN + q0w + g * 16 + l15) * ND;
#pragma unroll
        for (int ds = 0; ds < 8; ++ds)
            *reinterpret_cast<f32x4*>(op + rowbase + 16 * ds + 4 * lhi) = acc[g][ds];
    }
    if (lhi == 0) {
#pragma unroll
        for (int g = 0; g < 2; ++g) {
            size_t gr = bN + q0w + g * 16 + l15;
            *reinterpret_cast<float2*>(ml + ((size_t)sp * NR + gr) * 2) =
                make_float2(m_run[g], l_part[g]);
        }
    }
}

// ---------------- Kernel 3: merge the KV-splits (m is log2-domain) -------------
__global__ __launch_bounds__(256) void merge_splits(
    float* __restrict__ out, const float* __restrict__ opart1,
    const float* __restrict__ ml, int nsplit)
{
    int idx = blockIdx.x * 256 + threadIdx.x;
    int row = idx >> 5;
    int d4 = (idx & 31) * 4;
    float mmax = ml[(size_t)row * 2];
    for (int sp = 1; sp < nsplit; ++sp)
        mmax = fmaxf(mmax, ml[((size_t)sp * NR + row) * 2]);
    f32x4 o0 = *reinterpret_cast<const f32x4*>(out + (size_t)row * ND + d4);
    float w0 = exp2f(ml[(size_t)row * 2] - mmax);
    float lsum = ml[(size_t)row * 2 + 1] * w0;
    f32x4 acc;
#pragma unroll
    for (int j = 0; j < 4; ++j) acc[j] = o0[j] * w0;
    for (int sp = 1; sp < nsplit; ++sp) {
        float m_s = ml[((size_t)sp * NR + row) * 2];
        float l_s = ml[((size_t)sp * NR + row) * 2 + 1];
        float ws_ = exp2f(m_s - mmax);
        f32x4 os = *reinterpret_cast<const f32x4*>(opart1 + ((size_t)(sp - 1) * NR + row) * ND + d4);
#pragma unroll
        for (int j = 0; j < 4; ++j) acc[j] += os[j] * ws_;
        lsum += l_s * ws_;
    }
    float inv = 1.0f / lsum;
    f32x4 r;
#pragma unroll
    for (int j = 0; j < 4; ++j) r[j] = acc[j] * inv;
    *reinterpret_cast<f32x4*>(out + (size_t)row * ND + d4) = r;
}

extern "C" void kernel_launch(void* const* d_in, const int* in_sizes, int n_in,
                              void* d_out, int out_size, void* d_ws, size_t ws_size,
                              hipStream_t stream) {
    const float* h  = (const float*)d_in[0];
    const int* adj  = (const int*)d_in[1];
    const float* Wq = (const float*)d_in[2];
    const float* bq = (const float*)d_in[3];
    const float* Wk = (const float*)d_in[4];
    const float* bk = (const float*)d_in[5];
    const float* Wv = (const float*)d_in[6];
    const float* bv = (const float*)d_in[7];
    float* out = (float*)d_out;

    unsigned short* qws  = (unsigned short*)d_ws;
    unsigned short* kws  = qws + QKVE;
    unsigned short* vsws = kws + QKVE;
    float* opart1 = (float*)(vsws + QKVE);

    const size_t need4 = 3 * QKVE * 2 + 3 * QKVE * 4 + 4 * (size_t)NR * 2 * 4;
    const int nsplit = (ws_size >= need4) ? 4 : 2;
    float* mlws = opart1 + (size_t)(nsplit - 1) * NR * ND;
    const int ntl = (NN / KVB) / nsplit;                          // 32 or 64

    // 1/(sqrt(128) * ln2): scores land in log2 units -> exp2 softmax
    const float qscale = (float)(0.08838834764831845 / 0.6931471805599453);

    qkv_proj<<<dim3(768), 256, 0, stream>>>(
        h, Wq, bq, Wk, bk, Wv, bv, qws, kws, vsws, qscale);
    attn<<<dim3(32 * 4 * nsplit), 256, 0, stream>>>(
        qws, kws, vsws, adj, out, opart1, mlws, ntl);
    merge_splits<<<dim3(NR * 32 / 256), 256, 0, stream>>>(out, opart1, mlws, nsplit);
}